// Round 5
// baseline (355.061 us; speedup 1.0000x reference)
//
#include <hip/hip_runtime.h>
#include <hip/hip_fp16.h>

#define N_NODES 100000
#define EDGES   1600000
#define D       128
#define BN_EPS  1e-5f
#define TM      64                        // rows per GEMM tile
#define NT      ((N_NODES + TM - 1) / TM) // 1563 row tiles
#define GGRID   782                       // gemm grid: 2 tiles/block, ~3 blocks/CU
#define NB      ((N_NODES + 255) >> 8)    // 391 coarse buckets (256 nodes each)
#define SLOT    9216                      // fixed slot per bucket: mean 8192 + 11 sigma
#define L1E     8                         // EDGES per thread (emits 2 pairs each)
#define L1TILE  (256 * L1E)               // 2048 edges per tile

typedef __attribute__((ext_vector_type(8))) short short8;
typedef __attribute__((ext_vector_type(4))) float f32x4;

__device__ __forceinline__ unsigned short bf_hi(float f) {
    unsigned u = __float_as_uint(f);
    unsigned t = u + 0x7FFF + ((u >> 16) & 1);
    return (unsigned short)(t >> 16);
}
__device__ __forceinline__ float bf_val(unsigned short h) {
    return __uint_as_float(((unsigned)h) << 16);
}

// ---------------------------------------------------------------------------
// K0: convert x -> fp16 mirror; zero stats(2048f)+gcur(512i); split W1/W2
// ---------------------------------------------------------------------------
__global__ void convert_zero(const float* __restrict__ x, __half* __restrict__ xh,
                             int* __restrict__ zbase,
                             const float* __restrict__ W1, const float* __restrict__ W2,
                             unsigned short* __restrict__ w1h, unsigned short* __restrict__ w1l,
                             unsigned short* __restrict__ w2h, unsigned short* __restrict__ w2l) {
    int gid = blockIdx.x * blockDim.x + threadIdx.x;
    if (gid < 2560) zbase[gid] = 0;
    if (gid < 16384) {
        float f = W1[gid];
        unsigned short h = bf_hi(f);
        w1h[gid] = h;
        w1l[gid] = bf_hi(f - bf_val(h));
    } else if (gid < 32768) {
        int j = gid - 16384;
        float f = W2[j];
        unsigned short h = bf_hi(f);
        w2h[j] = h;
        w2l[j] = bf_hi(f - bf_val(h));
    }
    const int n4 = N_NODES * (D / 4);
    if (gid < n4) {
        float4 v = ((const float4*)x)[gid];
        __half2 h0 = __float22half2_rn(make_float2(v.x, v.y));
        __half2 h1 = __float22half2_rn(make_float2(v.z, v.w));
        ((__half2*)xh)[(long long)gid * 2 + 0] = h0;
        ((__half2*)xh)[(long long)gid * 2 + 1] = h1;
    }
}

// ---------------------------------------------------------------------------
// K3a: coarse-bucket partition into fixed slots. Single pass over E edges,
// each emits BOTH directions (halves the ei read traffic).
// pairs entry: (local_dst<<17) | src   (src < 2^17, local_dst < 256)
// ---------------------------------------------------------------------------
__launch_bounds__(256)
__global__ void partition_pairs(const int* __restrict__ ei, int* __restrict__ gcur,
                                int* __restrict__ pairs) {
    __shared__ int cnt[NB];
    __shared__ int cbase[NB];
    const int tid = threadIdx.x;
    for (int i = tid; i < NB; i += 256) cnt[i] = 0;
    __syncthreads();

    int bbA[L1E], rrA[L1E], pkA[L1E];
    int bbB[L1E], rrB[L1E], pkB[L1E];
    const int t0 = blockIdx.x * L1TILE + tid;
#pragma unroll
    for (int j = 0; j < L1E; ++j) {
        int t = t0 + j * 256;
        bbA[j] = -1;
        bbB[j] = -1;
        if (t < EDGES) {
            int s = ei[t];
            int d = ei[EDGES + t];
            bbA[j] = d >> 8;                     // aggr[d] += x[s]
            pkA[j] = ((d & 255) << 17) | s;
            rrA[j] = atomicAdd(&cnt[bbA[j]], 1);
            bbB[j] = s >> 8;                     // aggr[s] += x[d]
            pkB[j] = ((s & 255) << 17) | d;
            rrB[j] = atomicAdd(&cnt[bbB[j]], 1);
        }
    }
    __syncthreads();
    for (int i = tid; i < NB; i += 256) {
        int c = cnt[i];
        cbase[i] = c ? (i * SLOT + atomicAdd(&gcur[i], c)) : 0;
    }
    __syncthreads();
#pragma unroll
    for (int j = 0; j < L1E; ++j) {
        if (bbA[j] >= 0) {
            pairs[cbase[bbA[j]] + rrA[j]] = pkA[j];
            pairs[cbase[bbB[j]] + rrB[j]] = pkB[j];
        }
    }
}

// ---------------------------------------------------------------------------
// K3b: per-bucket: stage slot into LDS, count node degrees, scan, write
// ofs/oen, place adj IN-PLACE over the pairs slot.
// ---------------------------------------------------------------------------
__launch_bounds__(256)
__global__ void bucket_fill(int* __restrict__ pairs, const int* __restrict__ gcur,
                            int* __restrict__ ofs, int* __restrict__ oen) {
    __shared__ int sP[SLOT];     // 36.9 KB staged edges
    __shared__ int lc[256];
    __shared__ int cur[256];
    const int b    = blockIdx.x;
    const int tid  = threadIdx.x;
    const int base = b * SLOT;
    const int m    = min(gcur[b], SLOT);   // clamp: LDS-overflow guard
    for (int i = tid; i < m; i += 256) sP[i] = pairs[base + i];
    lc[tid] = 0;
    __syncthreads();
    for (int i = tid; i < m; i += 256) atomicAdd(&lc[sP[i] >> 17], 1);
    __syncthreads();
    int v = lc[tid];
    for (int d = 1; d < 256; d <<= 1) {
        int u = (tid >= d) ? lc[tid - d] : 0;
        __syncthreads();
        lc[tid] += u;
        __syncthreads();
    }
    int abs0 = base + lc[tid] - v;
    cur[tid] = abs0;
    const int n = (b << 8) + tid;
    if (n < N_NODES) { ofs[n] = abs0; oen[n] = abs0 + v; }
    __syncthreads();
    for (int i = tid; i < m; i += 256) {
        int p = sP[i];
        int r = atomicAdd(&cur[p >> 17], 1);
        pairs[r] = p & 0x1FFFF;
    }
}

// ---------------------------------------------------------------------------
// K4: gather-aggregate (node per wave, 8 rows in flight); self term from the
// fp16 mirror (its row is L2-hot); split-bf16 out. Two half-launches.
// ---------------------------------------------------------------------------
__launch_bounds__(256)
__global__ void gather_aggr(const __half* __restrict__ xh,
                            const int* __restrict__ adj, const int* __restrict__ ofs,
                            const int* __restrict__ oen, const float* __restrict__ eps_p,
                            unsigned int* __restrict__ hh, unsigned int* __restrict__ hl,
                            int nbase) {
    int node = nbase + blockIdx.x * 4 + (threadIdx.x >> 6);
    if (node >= N_NODES) return;
    int lane = threadIdx.x & 63;
    int b = ofs[node];
    int e = oen[node];
    const __half2* xp = (const __half2*)xh;
    float ax = 0.f, ay = 0.f;
    int i = b;
    for (; i + 8 <= e; i += 8) {
        int n0 = adj[i],     n1 = adj[i + 1], n2 = adj[i + 2], n3 = adj[i + 3];
        int n4 = adj[i + 4], n5 = adj[i + 5], n6 = adj[i + 6], n7 = adj[i + 7];
        __half2 v0 = xp[(unsigned)n0 * 64u + lane];
        __half2 v1 = xp[(unsigned)n1 * 64u + lane];
        __half2 v2 = xp[(unsigned)n2 * 64u + lane];
        __half2 v3 = xp[(unsigned)n3 * 64u + lane];
        __half2 v4 = xp[(unsigned)n4 * 64u + lane];
        __half2 v5 = xp[(unsigned)n5 * 64u + lane];
        __half2 v6 = xp[(unsigned)n6 * 64u + lane];
        __half2 v7 = xp[(unsigned)n7 * 64u + lane];
        float2 f0 = __half22float2(v0);
        float2 f1 = __half22float2(v1);
        float2 f2 = __half22float2(v2);
        float2 f3 = __half22float2(v3);
        float2 f4 = __half22float2(v4);
        float2 f5 = __half22float2(v5);
        float2 f6 = __half22float2(v6);
        float2 f7 = __half22float2(v7);
        ax += ((f0.x + f1.x) + (f2.x + f3.x)) + ((f4.x + f5.x) + (f6.x + f7.x));
        ay += ((f0.y + f1.y) + (f2.y + f3.y)) + ((f4.y + f5.y) + (f6.y + f7.y));
    }
    for (; i + 4 <= e; i += 4) {
        int n0 = adj[i], n1 = adj[i + 1], n2 = adj[i + 2], n3 = adj[i + 3];
        __half2 v0 = xp[(unsigned)n0 * 64u + lane];
        __half2 v1 = xp[(unsigned)n1 * 64u + lane];
        __half2 v2 = xp[(unsigned)n2 * 64u + lane];
        __half2 v3 = xp[(unsigned)n3 * 64u + lane];
        float2 f0 = __half22float2(v0);
        float2 f1 = __half22float2(v1);
        float2 f2 = __half22float2(v2);
        float2 f3 = __half22float2(v3);
        ax += (f0.x + f1.x) + (f2.x + f3.x);
        ay += (f0.y + f1.y) + (f2.y + f3.y);
    }
    for (; i < e; ++i) {
        __half2 v = xp[(unsigned)adj[i] * 64u + lane];
        float2 f = __half22float2(v);
        ax += f.x;
        ay += f.y;
    }
    float2 xs = __half22float2(xp[(unsigned)node * 64u + lane]);
    float sc = 2.0f + eps_p[0];
    float ox = fmaf(sc, xs.x, ax);
    float oy = fmaf(sc, xs.y, ay);
    unsigned short hx = bf_hi(ox), hy = bf_hi(oy);
    unsigned short lx = bf_hi(ox - bf_val(hx)), ly = bf_hi(oy - bf_val(hy));
    hh[(long long)node * 64 + lane] = (unsigned)hx | ((unsigned)hy << 16);
    hl[(long long)node * 64 + lane] = (unsigned)lx | ((unsigned)ly << 16);
}

// ---------------------------------------------------------------------------
// K5: h1 = h_pre @ W1^T + b1 (persistent-B MFMA, grid-strided, prefetch) +
// register-accumulated BN stats flushed to 8 replicas at kernel end.
// ---------------------------------------------------------------------------
__launch_bounds__(256)
__global__ void gemm1_mfma(const unsigned short* __restrict__ hh,
                           const unsigned short* __restrict__ hl,
                           const unsigned short* __restrict__ w1h,
                           const unsigned short* __restrict__ w1l,
                           const float* __restrict__ b1, float* __restrict__ h1,
                           float* __restrict__ stats) {
    __shared__ unsigned short sH[TM][136];
    __shared__ unsigned short sL[TM][136];
    const int tid = threadIdx.x;
    const int wv  = tid >> 6;
    const int ln  = tid & 63;
    const int lc  = ln & 15;
    const int qd  = ln >> 4;
    const int sr  = tid >> 4;      // staging row base (0..15)
    const int sc8 = tid & 15;      // staging 8-short chunk

    short8 Bh[4][2], Bl[4][2];
#pragma unroll
    for (int kk = 0; kk < 4; ++kk)
#pragma unroll
        for (int tl = 0; tl < 2; ++tl) {
            int woff = (wv * 32 + tl * 16 + lc) * D + kk * 32 + qd * 8;
            Bh[kk][tl] = *(const short8*)(w1h + woff);
            Bl[kk][tl] = *(const short8*)(w1l + woff);
        }
    float bb[2];
    bb[0] = b1[wv * 32 + lc];
    bb[1] = b1[wv * 32 + 16 + lc];

    float sAcc[2] = {0.f, 0.f}, qAcc[2] = {0.f, 0.f};

    uint4 vh[4], vl[4];
    int tile = blockIdx.x;
#pragma unroll
    for (int i = 0; i < 4; ++i) {
        int gr = tile * TM + sr + i * 16;
        vh[i] = make_uint4(0, 0, 0, 0);
        vl[i] = make_uint4(0, 0, 0, 0);
        if (gr < N_NODES) {
            vh[i] = *(const uint4*)(hh + (long long)gr * D + sc8 * 8);
            vl[i] = *(const uint4*)(hl + (long long)gr * D + sc8 * 8);
        }
    }

    while (tile < NT) {
#pragma unroll
        for (int i = 0; i < 4; ++i) {
            *(uint4*)&sH[sr + i * 16][sc8 * 8] = vh[i];
            *(uint4*)&sL[sr + i * 16][sc8 * 8] = vl[i];
        }
        __syncthreads();
        int nxt = tile + GGRID;
        if (nxt < NT) {
#pragma unroll
            for (int i = 0; i < 4; ++i) {
                int gr = nxt * TM + sr + i * 16;
                vh[i] = make_uint4(0, 0, 0, 0);
                vl[i] = make_uint4(0, 0, 0, 0);
                if (gr < N_NODES) {
                    vh[i] = *(const uint4*)(hh + (long long)gr * D + sc8 * 8);
                    vl[i] = *(const uint4*)(hl + (long long)gr * D + sc8 * 8);
                }
            }
        }

        f32x4 acc[4][2];
#pragma unroll
        for (int m = 0; m < 4; ++m)
#pragma unroll
            for (int tl = 0; tl < 2; ++tl) acc[m][tl] = (f32x4){0.f, 0.f, 0.f, 0.f};

#pragma unroll
        for (int kk = 0; kk < 4; ++kk) {
#pragma unroll
            for (int m = 0; m < 4; ++m) {
                short8 ah = *(const short8*)&sH[m * 16 + lc][kk * 32 + qd * 8];
                short8 al = *(const short8*)&sL[m * 16 + lc][kk * 32 + qd * 8];
#pragma unroll
                for (int tl = 0; tl < 2; ++tl) {
                    acc[m][tl] = __builtin_amdgcn_mfma_f32_16x16x32_bf16(ah, Bh[kk][tl], acc[m][tl], 0, 0, 0);
                    acc[m][tl] = __builtin_amdgcn_mfma_f32_16x16x32_bf16(al, Bh[kk][tl], acc[m][tl], 0, 0, 0);
                    acc[m][tl] = __builtin_amdgcn_mfma_f32_16x16x32_bf16(ah, Bl[kk][tl], acc[m][tl], 0, 0, 0);
                }
            }
        }

        const int row0 = tile * TM;
#pragma unroll
        for (int m = 0; m < 4; ++m)
#pragma unroll
            for (int tl = 0; tl < 2; ++tl) {
                int col = wv * 32 + tl * 16 + lc;
#pragma unroll
                for (int r = 0; r < 4; ++r) {
                    int grow = row0 + m * 16 + qd * 4 + r;
                    if (grow < N_NODES) {
                        float o = acc[m][tl][r] + bb[tl];
                        h1[(long long)grow * D + col] = o;
                        sAcc[tl] += o;
                        qAcc[tl] += o * o;
                    }
                }
            }
        __syncthreads();
        tile = nxt;
    }

    const int rep = blockIdx.x & 7;
#pragma unroll
    for (int tl = 0; tl < 2; ++tl) {
        float s = sAcc[tl], q = qAcc[tl];
        s += __shfl_xor(s, 16); s += __shfl_xor(s, 32);
        q += __shfl_xor(q, 16); q += __shfl_xor(q, 32);
        if (qd == 0) {
            int col = wv * 32 + tl * 16 + lc;
            atomicAdd(&stats[rep * 256 + col], s);
            atomicAdd(&stats[rep * 256 + 128 + col], q);
        }
    }
}

// ---------------------------------------------------------------------------
// K6: out = relu(bn(h1)) @ W2^T + b2  (persistent-B MFMA, grid-strided,
// prefetch), in-place on d_out. Reduces the 8 stat replicas in prologue.
// ---------------------------------------------------------------------------
__launch_bounds__(256)
__global__ void gemm2_mfma(float* __restrict__ h1out,
                           const unsigned short* __restrict__ w2h,
                           const unsigned short* __restrict__ w2l,
                           const float* __restrict__ b2, const float* __restrict__ stats,
                           const float* __restrict__ gamma, const float* __restrict__ beta) {
    __shared__ unsigned short sH[TM][136];
    __shared__ unsigned short sL[TM][136];
    __shared__ float sScale[128];
    __shared__ float sShift[128];
    const int tid = threadIdx.x;
    const int wv  = tid >> 6;
    const int ln  = tid & 63;
    const int lc  = ln & 15;
    const int qd  = ln >> 4;
    const int sr  = tid >> 5;      // staging row base (0..7)
    const int sc4 = tid & 31;      // staging float4 chunk

    if (tid < 128) {
        float s = 0.f, q = 0.f;
#pragma unroll
        for (int r = 0; r < 8; ++r) {
            s += stats[r * 256 + tid];
            q += stats[r * 256 + 128 + tid];
        }
        float mean = s * (1.0f / N_NODES);
        float var  = fmaxf(q * (1.0f / N_NODES) - mean * mean, 0.0f);
        float sc   = gamma[tid] * rsqrtf(var + BN_EPS);
        sScale[tid] = sc;
        sShift[tid] = beta[tid] - mean * sc;
    }

    short8 Bh[4][2], Bl[4][2];
#pragma unroll
    for (int kk = 0; kk < 4; ++kk)
#pragma unroll
        for (int tl = 0; tl < 2; ++tl) {
            int woff = (wv * 32 + tl * 16 + lc) * D + kk * 32 + qd * 8;
            Bh[kk][tl] = *(const short8*)(w2h + woff);
            Bl[kk][tl] = *(const short8*)(w2l + woff);
        }
    float bb[2];
    bb[0] = b2[wv * 32 + lc];
    bb[1] = b2[wv * 32 + 16 + lc];

    __syncthreads();   // sScale/sShift ready

    float4 pf[8];
    int tile = blockIdx.x;
#pragma unroll
    for (int i = 0; i < 8; ++i) {
        int gr = tile * TM + sr + i * 8;
        pf[i] = make_float4(0.f, 0.f, 0.f, 0.f);
        if (gr < N_NODES)
            pf[i] = *(const float4*)(h1out + (long long)gr * D + sc4 * 4);
    }

    while (tile < NT) {
        float4 scv = *(const float4*)&sScale[sc4 * 4];
        float4 shv = *(const float4*)&sShift[sc4 * 4];
#pragma unroll
        for (int i = 0; i < 8; ++i) {
            int gr = tile * TM + sr + i * 8;
            float4 v = pf[i];
            if (gr < N_NODES) {
                v.x = fmaxf(0.f, fmaf(v.x, scv.x, shv.x));
                v.y = fmaxf(0.f, fmaf(v.y, scv.y, shv.y));
                v.z = fmaxf(0.f, fmaf(v.z, scv.z, shv.z));
                v.w = fmaxf(0.f, fmaf(v.w, scv.w, shv.w));
            } else {
                v = make_float4(0.f, 0.f, 0.f, 0.f);
            }
            unsigned short h0 = bf_hi(v.x), h1b = bf_hi(v.y), h2 = bf_hi(v.z), h3 = bf_hi(v.w);
            unsigned short l0 = bf_hi(v.x - bf_val(h0)), l1 = bf_hi(v.y - bf_val(h1b));
            unsigned short l2 = bf_hi(v.z - bf_val(h2)), l3 = bf_hi(v.w - bf_val(h3));
            int r = sr + i * 8;
            *(uint2*)&sH[r][sc4 * 4] = make_uint2((unsigned)h0 | ((unsigned)h1b << 16),
                                                  (unsigned)h2 | ((unsigned)h3 << 16));
            *(uint2*)&sL[r][sc4 * 4] = make_uint2((unsigned)l0 | ((unsigned)l1 << 16),
                                                  (unsigned)l2 | ((unsigned)l3 << 16));
        }
        __syncthreads();
        int nxt = tile + GGRID;
        if (nxt < NT) {
#pragma unroll
            for (int i = 0; i < 8; ++i) {
                int gr = nxt * TM + sr + i * 8;
                pf[i] = make_float4(0.f, 0.f, 0.f, 0.f);
                if (gr < N_NODES)
                    pf[i] = *(const float4*)(h1out + (long long)gr * D + sc4 * 4);
            }
        }

        f32x4 acc[4][2];
#pragma unroll
        for (int m = 0; m < 4; ++m)
#pragma unroll
            for (int tl = 0; tl < 2; ++tl) acc[m][tl] = (f32x4){0.f, 0.f, 0.f, 0.f};

#pragma unroll
        for (int kk = 0; kk < 4; ++kk) {
#pragma unroll
            for (int m = 0; m < 4; ++m) {
                short8 ah = *(const short8*)&sH[m * 16 + lc][kk * 32 + qd * 8];
                short8 al = *(const short8*)&sL[m * 16 + lc][kk * 32 + qd * 8];
#pragma unroll
                for (int tl = 0; tl < 2; ++tl) {
                    acc[m][tl] = __builtin_amdgcn_mfma_f32_16x16x32_bf16(ah, Bh[kk][tl], acc[m][tl], 0, 0, 0);
                    acc[m][tl] = __builtin_amdgcn_mfma_f32_16x16x32_bf16(al, Bh[kk][tl], acc[m][tl], 0, 0, 0);
                    acc[m][tl] = __builtin_amdgcn_mfma_f32_16x16x32_bf16(ah, Bl[kk][tl], acc[m][tl], 0, 0, 0);
                }
            }
        }

        const int row0 = tile * TM;
#pragma unroll
        for (int m = 0; m < 4; ++m)
#pragma unroll
            for (int tl = 0; tl < 2; ++tl) {
                int col = wv * 32 + tl * 16 + lc;
#pragma unroll
                for (int r = 0; r < 4; ++r) {
                    int grow = row0 + m * 16 + qd * 4 + r;
                    if (grow < N_NODES)
                        h1out[(long long)grow * D + col] = acc[m][tl][r] + bb[tl];
                }
            }
        __syncthreads();
        tile = nxt;
    }
}

// ---------------------------------------------------------------------------
extern "C" void kernel_launch(void* const* d_in, const int* in_sizes, int n_in,
                              void* d_out, int out_size, void* d_ws, size_t ws_size,
                              hipStream_t stream) {
    const float* x     = (const float*)d_in[0];
    const int*   ei    = (const int*)d_in[1];
    const float* eps_p = (const float*)d_in[2];
    const float* W1    = (const float*)d_in[3];
    const float* b1    = (const float*)d_in[4];
    const float* gamma = (const float*)d_in[5];
    const float* beta  = (const float*)d_in[6];
    const float* W2    = (const float*)d_in[7];
    const float* b2    = (const float*)d_in[8];

    // workspace layout (~52.5 MB)
    unsigned int* hh  = (unsigned int*)d_ws;                  // N*64 uints: hpre hi
    unsigned int* hl  = hh + (long long)N_NODES * 64;         // hpre lo
    float* stats = (float*)(hl + (long long)N_NODES * 64);    // 2048 floats (8 replicas)
    int*   gcur  = (int*)(stats + 2048);                      // 512 ints (zeroed w/ stats)
    int*   ofs   = gcur + 512;                                // N ints
    int*   oen   = ofs + N_NODES;                             // N ints
    unsigned short* w1h = (unsigned short*)(oen + N_NODES);
    unsigned short* w1l = w1h + 16384;
    unsigned short* w2h = w1l + 16384;
    unsigned short* w2l = w2h + 16384;

    float* out   = (float*)d_out;                             // h1 scratch + final out
    __half* xh   = (__half*)d_out;                            // fp16 mirror: d_out[0:25.6MB]
    int*  pairs  = (int*)((char*)d_out + (size_t)N_NODES * 256);  // slot region, 14.4MB
    int*  adj    = pairs;                                     // adj aliases pairs (in-place)

    {   // K0: fp16 convert + zero stats/gcur + split W
        int grid = (N_NODES * (D / 4) + 255) / 256;
        convert_zero<<<grid, 256, 0, stream>>>(x, xh, (int*)stats,
                                               W1, W2, w1h, w1l, w2h, w2l);
    }
    {   // K3a: coarse-bucket partition (1 pass over E edges, 2 pairs each)
        int grid = (EDGES + L1TILE - 1) / L1TILE;
        partition_pairs<<<grid, 256, 0, stream>>>(ei, gcur, pairs);
    }
    {   // K3b: per-bucket LDS-staged count+scan+place -> ofs/oen, adj in-place
        bucket_fill<<<NB, 256, 0, stream>>>(pairs, gcur, ofs, oen);
    }
    {   // K4: gather-aggregate (two half-launches for profiler visibility)
        int half = N_NODES / 2;                               // 50000
        int grid = (half + 3) / 4;
        gather_aggr<<<grid, 256, 0, stream>>>(xh, adj, ofs, oen, eps_p, hh, hl, 0);
        int grid2 = (N_NODES - half + 3) / 4;
        gather_aggr<<<grid2, 256, 0, stream>>>(xh, adj, ofs, oen, eps_p, hh, hl, half);
    }
    {   // K5: persistent-B MFMA GEMM1 + BN stats (h1 -> d_out)
        gemm1_mfma<<<GGRID, 256, 0, stream>>>((const unsigned short*)hh, (const unsigned short*)hl,
                                              w1h, w1l, b1, out, stats);
    }
    {   // K6: BN finalize + ReLU + persistent-B MFMA GEMM2, in-place on d_out
        gemm2_mfma<<<GGRID, 256, 0, stream>>>(out, w2h, w2l, b2, stats, gamma, beta);
    }
}

// Round 7
// 344.977 us; speedup vs baseline: 1.0292x; 1.0292x over previous
//
#include <hip/hip_runtime.h>
#include <hip/hip_fp16.h>

#define N_NODES 100000
#define EDGES   1600000
#define D       128
#define BN_EPS  1e-5f
#define TM      64                        // rows per GEMM tile
#define NT      ((N_NODES + TM - 1) / TM) // 1563 row tiles
#define GGRID   782                       // gemm grid: 2 tiles/block
#define NB      ((N_NODES + 255) >> 8)    // 391 coarse buckets (256 nodes each)
#define SLOT    9216                      // fixed slot per bucket: mean 8192 + 11 sigma
#define L1E     8                         // edges per thread (emits 2 pairs each)
#define L1TILE  (256 * L1E)               // 2048 edges per tile
#define GBLKS   1536                      // gather blocks (persistent, grid-stride)
#define GWAVES  (GBLKS * 4)
#define NREP    32                        // BN-stat replicas

typedef __attribute__((ext_vector_type(8))) short short8;
typedef __attribute__((ext_vector_type(4))) float f32x4;

__device__ __forceinline__ unsigned short bf_hi(float f) {
    unsigned u = __float_as_uint(f);
    unsigned t = u + 0x7FFF + ((u >> 16) & 1);
    return (unsigned short)(t >> 16);
}
__device__ __forceinline__ float bf_val(unsigned short h) {
    return __uint_as_float(((unsigned)h) << 16);
}

// ---------------------------------------------------------------------------
// K0: zero stats(8192f)+gcur(512i); split W1/W2 into bf16 hi/lo
// ---------------------------------------------------------------------------
__global__ void zero_split(int* __restrict__ zbase,
                           const float* __restrict__ W1, const float* __restrict__ W2,
                           unsigned short* __restrict__ w1h, unsigned short* __restrict__ w1l,
                           unsigned short* __restrict__ w2h, unsigned short* __restrict__ w2l) {
    int gid = blockIdx.x * blockDim.x + threadIdx.x;   // 32768 threads
    if (gid < 8704) zbase[gid] = 0;
    if (gid < 16384) {
        float f = W1[gid];
        unsigned short h = bf_hi(f);
        w1h[gid] = h;
        w1l[gid] = bf_hi(f - bf_val(h));
    } else {
        int j = gid - 16384;
        float f = W2[j];
        unsigned short h = bf_hi(f);
        w2h[j] = h;
        w2l[j] = bf_hi(f - bf_val(h));
    }
}

// ---------------------------------------------------------------------------
// K3a: coarse-bucket partition into fixed slots. Single pass over E edges,
// each emits BOTH directions. pairs entry: (local_dst<<17) | src
// ---------------------------------------------------------------------------
__launch_bounds__(256)
__global__ void partition_pairs(const int* __restrict__ ei, int* __restrict__ gcur,
                                int* __restrict__ pairs) {
    __shared__ int cnt[NB];
    __shared__ int cbase[NB];
    const int tid = threadIdx.x;
    for (int i = tid; i < NB; i += 256) cnt[i] = 0;
    __syncthreads();

    int bbA[L1E], rrA[L1E], pkA[L1E];
    int bbB[L1E], rrB[L1E], pkB[L1E];
    const int t0 = blockIdx.x * L1TILE + tid;
#pragma unroll
    for (int j = 0; j < L1E; ++j) {
        int t = t0 + j * 256;
        bbA[j] = -1;
        bbB[j] = -1;
        if (t < EDGES) {
            int s = ei[t];
            int d = ei[EDGES + t];
            bbA[j] = d >> 8;                     // aggr[d] += y[s]
            pkA[j] = ((d & 255) << 17) | s;
            rrA[j] = atomicAdd(&cnt[bbA[j]], 1);
            bbB[j] = s >> 8;                     // aggr[s] += y[d]
            pkB[j] = ((s & 255) << 17) | d;
            rrB[j] = atomicAdd(&cnt[bbB[j]], 1);
        }
    }
    __syncthreads();
    for (int i = tid; i < NB; i += 256) {
        int c = cnt[i];
        cbase[i] = c ? (i * SLOT + atomicAdd(&gcur[i], c)) : 0;
    }
    __syncthreads();
#pragma unroll
    for (int j = 0; j < L1E; ++j) {
        if (bbA[j] >= 0) {
            pairs[cbase[bbA[j]] + rrA[j]] = pkA[j];
            pairs[cbase[bbB[j]] + rrB[j]] = pkB[j];
        }
    }
}

// ---------------------------------------------------------------------------
// K3b: per-bucket: stage slot into LDS, count node degrees, scan, write
// ofs/oen, place adj IN-PLACE over the pairs slot.
// ---------------------------------------------------------------------------
__launch_bounds__(256)
__global__ void bucket_fill(int* __restrict__ pairs, const int* __restrict__ gcur,
                            int* __restrict__ ofs, int* __restrict__ oen) {
    __shared__ int sP[SLOT];     // 36.9 KB staged edges
    __shared__ int lc[256];
    __shared__ int cur[256];
    const int b    = blockIdx.x;
    const int tid  = threadIdx.x;
    const int base = b * SLOT;
    const int m    = min(gcur[b], SLOT);   // clamp: LDS-overflow guard
    for (int i = tid; i < m; i += 256) sP[i] = pairs[base + i];
    lc[tid] = 0;
    __syncthreads();
    for (int i = tid; i < m; i += 256) atomicAdd(&lc[sP[i] >> 17], 1);
    __syncthreads();
    int v = lc[tid];
    for (int d = 1; d < 256; d <<= 1) {
        int u = (tid >= d) ? lc[tid - d] : 0;
        __syncthreads();
        lc[tid] += u;
        __syncthreads();
    }
    int abs0 = base + lc[tid] - v;
    cur[tid] = abs0;
    const int n = (b << 8) + tid;
    if (n < N_NODES) { ofs[n] = abs0; oen[n] = abs0 + v; }
    __syncthreads();
    for (int i = tid; i < m; i += 256) {
        int p = sP[i];
        int r = atomicAdd(&cur[p >> 17], 1);
        pairs[r] = p & 0x1FFFF;
    }
}

// ---------------------------------------------------------------------------
// K-G0: y = x @ W1^T  (persistent-B MFMA, grid-strided, prefetch; split-bf16
// A staged inline from fp32 x; NO bias — b1 is applied once in the gather).
// Output: fp16 y mirror (the gather's working set).
// ---------------------------------------------------------------------------
__launch_bounds__(256)
__global__ void gemm0_mfma(const float* __restrict__ x,
                           const unsigned short* __restrict__ w1h,
                           const unsigned short* __restrict__ w1l,
                           __half* __restrict__ yh) {
    __shared__ unsigned short sH[TM][136];
    __shared__ unsigned short sL[TM][136];
    const int tid = threadIdx.x;
    const int wv  = tid >> 6;
    const int ln  = tid & 63;
    const int lc  = ln & 15;
    const int qd  = ln >> 4;
    const int sr  = tid >> 5;      // staging row base (0..7)
    const int sc4 = tid & 31;      // staging float4 chunk

    short8 Bh[4][2], Bl[4][2];
#pragma unroll
    for (int kk = 0; kk < 4; ++kk)
#pragma unroll
        for (int tl = 0; tl < 2; ++tl) {
            int woff = (wv * 32 + tl * 16 + lc) * D + kk * 32 + qd * 8;
            Bh[kk][tl] = *(const short8*)(w1h + woff);
            Bl[kk][tl] = *(const short8*)(w1l + woff);
        }

    float4 pf[8];
    int tile = blockIdx.x;
#pragma unroll
    for (int i = 0; i < 8; ++i) {
        int gr = tile * TM + sr + i * 8;
        pf[i] = make_float4(0.f, 0.f, 0.f, 0.f);
        if (gr < N_NODES)
            pf[i] = *(const float4*)(x + (long long)gr * D + sc4 * 4);
    }

    while (tile < NT) {
#pragma unroll
        for (int i = 0; i < 8; ++i) {
            float4 v = pf[i];
            unsigned short h0 = bf_hi(v.x), h1b = bf_hi(v.y), h2 = bf_hi(v.z), h3 = bf_hi(v.w);
            unsigned short l0 = bf_hi(v.x - bf_val(h0)), l1 = bf_hi(v.y - bf_val(h1b));
            unsigned short l2 = bf_hi(v.z - bf_val(h2)), l3 = bf_hi(v.w - bf_val(h3));
            int r = sr + i * 8;
            *(uint2*)&sH[r][sc4 * 4] = make_uint2((unsigned)h0 | ((unsigned)h1b << 16),
                                                  (unsigned)h2 | ((unsigned)h3 << 16));
            *(uint2*)&sL[r][sc4 * 4] = make_uint2((unsigned)l0 | ((unsigned)l1 << 16),
                                                  (unsigned)l2 | ((unsigned)l3 << 16));
        }
        __syncthreads();
        int nxt = tile + GGRID;
        if (nxt < NT) {
#pragma unroll
            for (int i = 0; i < 8; ++i) {
                int gr = nxt * TM + sr + i * 8;
                pf[i] = make_float4(0.f, 0.f, 0.f, 0.f);
                if (gr < N_NODES)
                    pf[i] = *(const float4*)(x + (long long)gr * D + sc4 * 4);
            }
        }

        f32x4 acc[4][2];
#pragma unroll
        for (int m = 0; m < 4; ++m)
#pragma unroll
            for (int tl = 0; tl < 2; ++tl) acc[m][tl] = (f32x4){0.f, 0.f, 0.f, 0.f};

#pragma unroll
        for (int kk = 0; kk < 4; ++kk) {
#pragma unroll
            for (int m = 0; m < 4; ++m) {
                short8 ah = *(const short8*)&sH[m * 16 + lc][kk * 32 + qd * 8];
                short8 al = *(const short8*)&sL[m * 16 + lc][kk * 32 + qd * 8];
#pragma unroll
                for (int tl = 0; tl < 2; ++tl) {
                    acc[m][tl] = __builtin_amdgcn_mfma_f32_16x16x32_bf16(ah, Bh[kk][tl], acc[m][tl], 0, 0, 0);
                    acc[m][tl] = __builtin_amdgcn_mfma_f32_16x16x32_bf16(al, Bh[kk][tl], acc[m][tl], 0, 0, 0);
                    acc[m][tl] = __builtin_amdgcn_mfma_f32_16x16x32_bf16(ah, Bl[kk][tl], acc[m][tl], 0, 0, 0);
                }
            }
        }

        const int row0 = tile * TM;
#pragma unroll
        for (int m = 0; m < 4; ++m)
#pragma unroll
            for (int tl = 0; tl < 2; ++tl) {
                int col = wv * 32 + tl * 16 + lc;
#pragma unroll
                for (int r = 0; r < 4; ++r) {
                    int grow = row0 + m * 16 + qd * 4 + r;
                    if (grow < N_NODES)
                        yh[(long long)grow * D + col] = __float2half(acc[m][tl][r]);
                }
            }
        __syncthreads();
        tile = nxt;
    }
}

// ---------------------------------------------------------------------------
// K4: gather-aggregate on y: h1_i = (2+eps)*y_i + sum_nbr y_j + b1.
// Persistent grid-stride (node per wave); BN stats accumulated in registers,
// block-reduced in LDS, flushed via atomics into NREP replicas.
// ---------------------------------------------------------------------------
__launch_bounds__(256)
__global__ void gather_aggr(const __half* __restrict__ yh,
                            const int* __restrict__ adj, const int* __restrict__ ofs,
                            const int* __restrict__ oen, const float* __restrict__ eps_p,
                            const float* __restrict__ b1,
                            float* __restrict__ h1, float* __restrict__ stats) {
    const int wv   = threadIdx.x >> 6;
    const int lane = threadIdx.x & 63;
    const int wave = blockIdx.x * 4 + wv;
    const __half2* xp = (const __half2*)yh;
    const float sc = 2.0f + eps_p[0];
    const float2 b1c = ((const float2*)b1)[lane];
    float sx = 0.f, sy = 0.f, qx = 0.f, qy = 0.f;

    for (int node = wave; node < N_NODES; node += GWAVES) {
        int b = ofs[node];
        int e = oen[node];
        float ax = 0.f, ay = 0.f;
        int i = b;
        for (; i + 8 <= e; i += 8) {
            int n0 = adj[i],     n1 = adj[i + 1], n2 = adj[i + 2], n3 = adj[i + 3];
            int n4 = adj[i + 4], n5 = adj[i + 5], n6 = adj[i + 6], n7 = adj[i + 7];
            __half2 v0 = xp[(unsigned)n0 * 64u + lane];
            __half2 v1 = xp[(unsigned)n1 * 64u + lane];
            __half2 v2 = xp[(unsigned)n2 * 64u + lane];
            __half2 v3 = xp[(unsigned)n3 * 64u + lane];
            __half2 v4 = xp[(unsigned)n4 * 64u + lane];
            __half2 v5 = xp[(unsigned)n5 * 64u + lane];
            __half2 v6 = xp[(unsigned)n6 * 64u + lane];
            __half2 v7 = xp[(unsigned)n7 * 64u + lane];
            float2 f0 = __half22float2(v0);
            float2 f1 = __half22float2(v1);
            float2 f2 = __half22float2(v2);
            float2 f3 = __half22float2(v3);
            float2 f4 = __half22float2(v4);
            float2 f5 = __half22float2(v5);
            float2 f6 = __half22float2(v6);
            float2 f7 = __half22float2(v7);
            ax += ((f0.x + f1.x) + (f2.x + f3.x)) + ((f4.x + f5.x) + (f6.x + f7.x));
            ay += ((f0.y + f1.y) + (f2.y + f3.y)) + ((f4.y + f5.y) + (f6.y + f7.y));
        }
        for (; i + 4 <= e; i += 4) {
            int n0 = adj[i], n1 = adj[i + 1], n2 = adj[i + 2], n3 = adj[i + 3];
            __half2 v0 = xp[(unsigned)n0 * 64u + lane];
            __half2 v1 = xp[(unsigned)n1 * 64u + lane];
            __half2 v2 = xp[(unsigned)n2 * 64u + lane];
            __half2 v3 = xp[(unsigned)n3 * 64u + lane];
            float2 f0 = __half22float2(v0);
            float2 f1 = __half22float2(v1);
            float2 f2 = __half22float2(v2);
            float2 f3 = __half22float2(v3);
            ax += (f0.x + f1.x) + (f2.x + f3.x);
            ay += (f0.y + f1.y) + (f2.y + f3.y);
        }
        for (; i < e; ++i) {
            __half2 v = xp[(unsigned)adj[i] * 64u + lane];
            float2 f = __half22float2(v);
            ax += f.x;
            ay += f.y;
        }
        float2 ys = __half22float2(xp[(unsigned)node * 64u + lane]);
        float ox = fmaf(sc, ys.x, ax) + b1c.x;
        float oy = fmaf(sc, ys.y, ay) + b1c.y;
        ((float2*)h1)[(long long)node * 64 + lane] = make_float2(ox, oy);
        sx += ox; sy += oy;
        qx += ox * ox; qy += oy * oy;
    }

    __shared__ float4 red[4][64];
    red[wv][lane] = make_float4(sx, sy, qx, qy);
    __syncthreads();
    if (wv == 0) {
        float4 a = red[0][lane], b4 = red[1][lane], c = red[2][lane], d4 = red[3][lane];
        float fx = (a.x + b4.x) + (c.x + d4.x);
        float fy = (a.y + b4.y) + (c.y + d4.y);
        float gx = (a.z + b4.z) + (c.z + d4.z);
        float gy = (a.w + b4.w) + (c.w + d4.w);
        float* st = stats + (blockIdx.x & (NREP - 1)) * 256;
        atomicAdd(&st[2 * lane],       fx);
        atomicAdd(&st[2 * lane + 1],   fy);
        atomicAdd(&st[128 + 2 * lane],     gx);
        atomicAdd(&st[128 + 2 * lane + 1], gy);
    }
}

// ---------------------------------------------------------------------------
// K6: out = relu(bn(h1)) @ W2^T + b2  (persistent-B MFMA, grid-strided,
// prefetch), in-place on d_out. Reduces the NREP stat replicas in prologue.
// ---------------------------------------------------------------------------
__launch_bounds__(256)
__global__ void gemm2_mfma(float* __restrict__ h1out,
                           const unsigned short* __restrict__ w2h,
                           const unsigned short* __restrict__ w2l,
                           const float* __restrict__ b2, const float* __restrict__ stats,
                           const float* __restrict__ gamma, const float* __restrict__ beta) {
    __shared__ unsigned short sH[TM][136];
    __shared__ unsigned short sL[TM][136];
    __shared__ float sScale[128];
    __shared__ float sShift[128];
    const int tid = threadIdx.x;
    const int wv  = tid >> 6;
    const int ln  = tid & 63;
    const int lc  = ln & 15;
    const int qd  = ln >> 4;
    const int sr  = tid >> 5;      // staging row base (0..7)
    const int sc4 = tid & 31;      // staging float4 chunk

    if (tid < 128) {
        float s = 0.f, q = 0.f;
#pragma unroll
        for (int r = 0; r < NREP; ++r) {
            s += stats[r * 256 + tid];
            q += stats[r * 256 + 128 + tid];
        }
        float mean = s * (1.0f / N_NODES);
        float var  = fmaxf(q * (1.0f / N_NODES) - mean * mean, 0.0f);
        float sc   = gamma[tid] * rsqrtf(var + BN_EPS);
        sScale[tid] = sc;
        sShift[tid] = beta[tid] - mean * sc;
    }

    short8 Bh[4][2], Bl[4][2];
#pragma unroll
    for (int kk = 0; kk < 4; ++kk)
#pragma unroll
        for (int tl = 0; tl < 2; ++tl) {
            int woff = (wv * 32 + tl * 16 + lc) * D + kk * 32 + qd * 8;
            Bh[kk][tl] = *(const short8*)(w2h + woff);
            Bl[kk][tl] = *(const short8*)(w2l + woff);
        }
    float bb[2];
    bb[0] = b2[wv * 32 + lc];
    bb[1] = b2[wv * 32 + 16 + lc];

    __syncthreads();   // sScale/sShift ready

    float4 pf[8];
    int tile = blockIdx.x;
#pragma unroll
    for (int i = 0; i < 8; ++i) {
        int gr = tile * TM + sr + i * 8;
        pf[i] = make_float4(0.f, 0.f, 0.f, 0.f);
        if (gr < N_NODES)
            pf[i] = *(const float4*)(h1out + (long long)gr * D + sc4 * 4);
    }

    while (tile < NT) {
        float4 scv = *(const float4*)&sScale[sc4 * 4];
        float4 shv = *(const float4*)&sShift[sc4 * 4];
#pragma unroll
        for (int i = 0; i < 8; ++i) {
            int gr = tile * TM + sr + i * 8;
            float4 v = pf[i];
            if (gr < N_NODES) {
                v.x = fmaxf(0.f, fmaf(v.x, scv.x, shv.x));
                v.y = fmaxf(0.f, fmaf(v.y, scv.y, shv.y));
                v.z = fmaxf(0.f, fmaf(v.z, scv.z, shv.z));
                v.w = fmaxf(0.f, fmaf(v.w, scv.w, shv.w));
            } else {
                v = make_float4(0.f, 0.f, 0.f, 0.f);
            }
            unsigned short h0 = bf_hi(v.x), h1b = bf_hi(v.y), h2 = bf_hi(v.z), h3 = bf_hi(v.w);
            unsigned short l0 = bf_hi(v.x - bf_val(h0)), l1 = bf_hi(v.y - bf_val(h1b));
            unsigned short l2 = bf_hi(v.z - bf_val(h2)), l3 = bf_hi(v.w - bf_val(h3));
            int r = sr + i * 8;
            *(uint2*)&sH[r][sc4 * 4] = make_uint2((unsigned)h0 | ((unsigned)h1b << 16),
                                                  (unsigned)h2 | ((unsigned)h3 << 16));
            *(uint2*)&sL[r][sc4 * 4] = make_uint2((unsigned)l0 | ((unsigned)l1 << 16),
                                                  (unsigned)l2 | ((unsigned)l3 << 16));
        }
        __syncthreads();
        int nxt = tile + GGRID;
        if (nxt < NT) {
#pragma unroll
            for (int i = 0; i < 8; ++i) {
                int gr = nxt * TM + sr + i * 8;
                pf[i] = make_float4(0.f, 0.f, 0.f, 0.f);
                if (gr < N_NODES)
                    pf[i] = *(const float4*)(h1out + (long long)gr * D + sc4 * 4);
            }
        }

        f32x4 acc[4][2];
#pragma unroll
        for (int m = 0; m < 4; ++m)
#pragma unroll
            for (int tl = 0; tl < 2; ++tl) acc[m][tl] = (f32x4){0.f, 0.f, 0.f, 0.f};

#pragma unroll
        for (int kk = 0; kk < 4; ++kk) {
#pragma unroll
            for (int m = 0; m < 4; ++m) {
                short8 ah = *(const short8*)&sH[m * 16 + lc][kk * 32 + qd * 8];
                short8 al = *(const short8*)&sL[m * 16 + lc][kk * 32 + qd * 8];
#pragma unroll
                for (int tl = 0; tl < 2; ++tl) {
                    acc[m][tl] = __builtin_amdgcn_mfma_f32_16x16x32_bf16(ah, Bh[kk][tl], acc[m][tl], 0, 0, 0);
                    acc[m][tl] = __builtin_amdgcn_mfma_f32_16x16x32_bf16(al, Bh[kk][tl], acc[m][tl], 0, 0, 0);
                    acc[m][tl] = __builtin_amdgcn_mfma_f32_16x16x32_bf16(ah, Bl[kk][tl], acc[m][tl], 0, 0, 0);
                }
            }
        }

        const int row0 = tile * TM;
#pragma unroll
        for (int m = 0; m < 4; ++m)
#pragma unroll
            for (int tl = 0; tl < 2; ++tl) {
                int col = wv * 32 + tl * 16 + lc;
#pragma unroll
                for (int r = 0; r < 4; ++r) {
                    int grow = row0 + m * 16 + qd * 4 + r;
                    if (grow < N_NODES)
                        h1out[(long long)grow * D + col] = acc[m][tl][r] + bb[tl];
                }
            }
        __syncthreads();
        tile = nxt;
    }
}

// ---------------------------------------------------------------------------
extern "C" void kernel_launch(void* const* d_in, const int* in_sizes, int n_in,
                              void* d_out, int out_size, void* d_ws, size_t ws_size,
                              hipStream_t stream) {
    const float* x     = (const float*)d_in[0];
    const int*   ei    = (const int*)d_in[1];
    const float* eps_p = (const float*)d_in[2];
    const float* W1    = (const float*)d_in[3];
    const float* b1    = (const float*)d_in[4];
    const float* gamma = (const float*)d_in[5];
    const float* beta  = (const float*)d_in[6];
    const float* W2    = (const float*)d_in[7];
    const float* b2    = (const float*)d_in[8];

    // workspace layout (~41 MB)
    __half* yh   = (__half*)d_ws;                             // N*128 halfs: y mirror (25.6MB)
    float*  stats = (float*)(yh + (long long)N_NODES * D);    // NREP*256 floats
    int*    gcur  = (int*)(stats + NREP * 256);               // 512 ints (zeroed w/ stats)
    int*    ofs   = gcur + 512;                               // N ints
    int*    oen   = ofs + N_NODES;                            // N ints
    unsigned short* w1h = (unsigned short*)(oen + N_NODES);
    unsigned short* w1l = w1h + 16384;
    unsigned short* w2h = w1l + 16384;
    unsigned short* w2l = w2h + 16384;
    int*    pairs = (int*)(w2l + 16384);                      // NB*SLOT ints (14.4MB)
    int*    adj   = pairs;                                    // adj aliases pairs (in-place)

    float* out = (float*)d_out;                               // h1 scratch + final out

    {   // K0: zero stats/gcur + split W1/W2
        zero_split<<<128, 256, 0, stream>>>((int*)stats, W1, W2, w1h, w1l, w2h, w2l);
    }
    {   // K3a: coarse-bucket partition (1 pass over E edges, 2 pairs each)
        int grid = (EDGES + L1TILE - 1) / L1TILE;
        partition_pairs<<<grid, 256, 0, stream>>>(ei, gcur, pairs);
    }
    {   // K3b: per-bucket LDS-staged count+scan+place -> ofs/oen, adj in-place
        bucket_fill<<<NB, 256, 0, stream>>>(pairs, gcur, ofs, oen);
    }
    {   // K-G0: y = x @ W1^T  -> fp16 mirror in ws
        gemm0_mfma<<<GGRID, 256, 0, stream>>>(x, w1h, w1l, yh);
    }
    {   // K4: gather-aggregate on y -> h1 (d_out) + BN stats
        gather_aggr<<<GBLKS, 256, 0, stream>>>(yh, adj, ofs, oen, eps_p, b1, out, stats);
    }
    {   // K6: BN finalize + ReLU + persistent-B MFMA GEMM2, in-place on d_out
        gemm2_mfma<<<GGRID, 256, 0, stream>>>(out, w2h, w2l, b2, stats, gamma, beta);
    }
}

// Round 9
// 329.888 us; speedup vs baseline: 1.0763x; 1.0457x over previous
//
#include <hip/hip_runtime.h>
#include <hip/hip_fp16.h>

#define N_NODES 100000
#define EDGES   1600000
#define D       128
#define BN_EPS  1e-5f
#define TM      64                        // rows per GEMM tile
#define NT      ((N_NODES + TM - 1) / TM) // 1563 row tiles
#define GGRID   782                       // gemm grid-stride: 2 tiles/block
#define NB      782                       // 128-node buckets
#define SLOT    4800                      // per-bucket slot: mean 4092 + 11 sigma
#define L1E     8                         // ei entries per thread (emits 2 pairs each)
#define L1TILE  (256 * L1E)               // 2048 ei entries per tile -> 782 tiles
#define GBLKS   1536                      // gather blocks (persistent, grid-stride)
#define GWAVES  (GBLKS * 4)
#define NREP    32                        // BN-stat replicas

typedef __attribute__((ext_vector_type(8))) short short8;
typedef __attribute__((ext_vector_type(4))) float f32x4;

__device__ __forceinline__ unsigned short bf_hi(float f) {
    unsigned u = __float_as_uint(f);
    unsigned t = u + 0x7FFF + ((u >> 16) & 1);
    return (unsigned short)(t >> 16);
}
__device__ __forceinline__ float bf_val(unsigned short h) {
    return __uint_as_float(((unsigned)h) << 16);
}

// ---------------------------------------------------------------------------
// K0: zero stats(8192f)+gcur(1024i); split W1/W2 into bf16 hi/lo
// ---------------------------------------------------------------------------
__global__ void zero_split(int* __restrict__ zbase,
                           const float* __restrict__ W1, const float* __restrict__ W2,
                           unsigned short* __restrict__ w1h, unsigned short* __restrict__ w1l,
                           unsigned short* __restrict__ w2h, unsigned short* __restrict__ w2l) {
    int gid = blockIdx.x * blockDim.x + threadIdx.x;   // 32768 threads
    if (gid < 9216) zbase[gid] = 0;
    if (gid < 16384) {
        float f = W1[gid];
        unsigned short h = bf_hi(f);
        w1h[gid] = h;
        w1l[gid] = bf_hi(f - bf_val(h));
    } else {
        int j = gid - 16384;
        float f = W2[j];
        unsigned short h = bf_hi(f);
        w2h[j] = h;
        w2l[j] = bf_hi(f - bf_val(h));
    }
}

// ---------------------------------------------------------------------------
// F1: heterogeneous fused kernel.
//   blocks [0, GGRID)          : gemm0  y = x @ W1^T -> fp16 mirror
//   blocks [GGRID, GGRID+782)  : K3a edge partition into 128-node buckets
// Independent data; partition LDS aliases the gemm tile buffers.
// pairs entry: (local_dst<<17) | src   (local_dst < 128, src < 2^17)
// ---------------------------------------------------------------------------
__launch_bounds__(256)
__global__ void fused_pg(const float* __restrict__ x,
                         const unsigned short* __restrict__ w1h,
                         const unsigned short* __restrict__ w1l,
                         __half* __restrict__ yh,
                         const int* __restrict__ ei, int* __restrict__ gcur,
                         int* __restrict__ pairs) {
    __shared__ unsigned short sH[TM][136];
    __shared__ unsigned short sL[TM][136];
    const int tid = threadIdx.x;

    if (blockIdx.x >= GGRID) {
        // ---------------- partition path ----------------
        int* cnt   = (int*)&sH[0][0];        // 782 ints
        int* cbase = cnt + NB;               // 782 ints  (6.3 KB total, aliased)
        for (int i = tid; i < NB; i += 256) cnt[i] = 0;
        __syncthreads();

        int bbA[L1E], rrA[L1E], pkA[L1E];
        int bbB[L1E], rrB[L1E], pkB[L1E];
        const int t0 = (blockIdx.x - GGRID) * L1TILE + tid;
#pragma unroll
        for (int j = 0; j < L1E; ++j) {
            int t = t0 + j * 256;
            bbA[j] = -1;
            bbB[j] = -1;
            if (t < EDGES) {
                int s = ei[t];
                int d = ei[EDGES + t];
                bbA[j] = d >> 7;                     // aggr[d] += y[s]
                pkA[j] = ((d & 127) << 17) | s;
                rrA[j] = atomicAdd(&cnt[bbA[j]], 1);
                bbB[j] = s >> 7;                     // aggr[s] += y[d]
                pkB[j] = ((s & 127) << 17) | d;
                rrB[j] = atomicAdd(&cnt[bbB[j]], 1);
            }
        }
        __syncthreads();
        for (int i = tid; i < NB; i += 256) {
            int c = cnt[i];
            cbase[i] = c ? (i * SLOT + atomicAdd(&gcur[i], c)) : 0;
        }
        __syncthreads();
#pragma unroll
        for (int j = 0; j < L1E; ++j) {
            if (bbA[j] >= 0) {
                pairs[cbase[bbA[j]] + rrA[j]] = pkA[j];
                pairs[cbase[bbB[j]] + rrB[j]] = pkB[j];
            }
        }
        return;
    }

    // ---------------- gemm0 path ----------------
    const int wv  = tid >> 6;
    const int ln  = tid & 63;
    const int lc  = ln & 15;
    const int qd  = ln >> 4;
    const int sr  = tid >> 5;      // staging row base (0..7)
    const int sc4 = tid & 31;      // staging float4 chunk

    short8 Bh[4][2], Bl[4][2];
#pragma unroll
    for (int kk = 0; kk < 4; ++kk)
#pragma unroll
        for (int tl = 0; tl < 2; ++tl) {
            int woff = (wv * 32 + tl * 16 + lc) * D + kk * 32 + qd * 8;
            Bh[kk][tl] = *(const short8*)(w1h + woff);
            Bl[kk][tl] = *(const short8*)(w1l + woff);
        }

    float4 pf[8];
    int tile = blockIdx.x;
#pragma unroll
    for (int i = 0; i < 8; ++i) {
        int gr = tile * TM + sr + i * 8;
        pf[i] = make_float4(0.f, 0.f, 0.f, 0.f);
        if (gr < N_NODES)
            pf[i] = *(const float4*)(x + (long long)gr * D + sc4 * 4);
    }

    while (tile < NT) {
#pragma unroll
        for (int i = 0; i < 8; ++i) {
            float4 v = pf[i];
            unsigned short h0 = bf_hi(v.x), h1b = bf_hi(v.y), h2 = bf_hi(v.z), h3 = bf_hi(v.w);
            unsigned short l0 = bf_hi(v.x - bf_val(h0)), l1 = bf_hi(v.y - bf_val(h1b));
            unsigned short l2 = bf_hi(v.z - bf_val(h2)), l3 = bf_hi(v.w - bf_val(h3));
            int r = sr + i * 8;
            *(uint2*)&sH[r][sc4 * 4] = make_uint2((unsigned)h0 | ((unsigned)h1b << 16),
                                                  (unsigned)h2 | ((unsigned)h3 << 16));
            *(uint2*)&sL[r][sc4 * 4] = make_uint2((unsigned)l0 | ((unsigned)l1 << 16),
                                                  (unsigned)l2 | ((unsigned)l3 << 16));
        }
        __syncthreads();
        int nxt = tile + GGRID;
        if (nxt < NT) {
#pragma unroll
            for (int i = 0; i < 8; ++i) {
                int gr = nxt * TM + sr + i * 8;
                pf[i] = make_float4(0.f, 0.f, 0.f, 0.f);
                if (gr < N_NODES)
                    pf[i] = *(const float4*)(x + (long long)gr * D + sc4 * 4);
            }
        }

        f32x4 acc[4][2];
#pragma unroll
        for (int m = 0; m < 4; ++m)
#pragma unroll
            for (int tl = 0; tl < 2; ++tl) acc[m][tl] = (f32x4){0.f, 0.f, 0.f, 0.f};

#pragma unroll
        for (int kk = 0; kk < 4; ++kk) {
#pragma unroll
            for (int m = 0; m < 4; ++m) {
                short8 ah = *(const short8*)&sH[m * 16 + lc][kk * 32 + qd * 8];
                short8 al = *(const short8*)&sL[m * 16 + lc][kk * 32 + qd * 8];
#pragma unroll
                for (int tl = 0; tl < 2; ++tl) {
                    acc[m][tl] = __builtin_amdgcn_mfma_f32_16x16x32_bf16(ah, Bh[kk][tl], acc[m][tl], 0, 0, 0);
                    acc[m][tl] = __builtin_amdgcn_mfma_f32_16x16x32_bf16(al, Bh[kk][tl], acc[m][tl], 0, 0, 0);
                    acc[m][tl] = __builtin_amdgcn_mfma_f32_16x16x32_bf16(ah, Bl[kk][tl], acc[m][tl], 0, 0, 0);
                }
            }
        }

        const int row0 = tile * TM;
#pragma unroll
        for (int m = 0; m < 4; ++m)
#pragma unroll
            for (int tl = 0; tl < 2; ++tl) {
                int col = wv * 32 + tl * 16 + lc;
#pragma unroll
                for (int r = 0; r < 4; ++r) {
                    int grow = row0 + m * 16 + qd * 4 + r;
                    if (grow < N_NODES)
                        yh[(long long)grow * D + col] = __float2half(acc[m][tl][r]);
                }
            }
        __syncthreads();
        tile = nxt;
    }
}

// ---------------------------------------------------------------------------
// K3b: per-128-node-bucket: stage slot into LDS, count node degrees, scan,
// write ofs/oen, place adj IN-PLACE over the pairs slot. 782 blocks.
// ---------------------------------------------------------------------------
__launch_bounds__(256)
__global__ void bucket_fill(int* __restrict__ pairs, const int* __restrict__ gcur,
                            int* __restrict__ ofs, int* __restrict__ oen) {
    __shared__ int sP[SLOT];     // 19.2 KB staged edges
    __shared__ int lc[128];
    __shared__ int cur[128];
    const int b    = blockIdx.x;
    const int tid  = threadIdx.x;
    const int base = b * SLOT;
    const int m    = min(gcur[b], SLOT);   // clamp: LDS-overflow guard
    for (int i = tid; i < m; i += 256) sP[i] = pairs[base + i];
    if (tid < 128) lc[tid] = 0;
    __syncthreads();
    for (int i = tid; i < m; i += 256) atomicAdd(&lc[sP[i] >> 17], 1);
    __syncthreads();
    int v = (tid < 128) ? lc[tid] : 0;
    for (int d = 1; d < 128; d <<= 1) {
        int u = (tid >= d && tid < 128) ? lc[tid - d] : 0;
        __syncthreads();
        if (tid < 128) lc[tid] += u;
        __syncthreads();
    }
    if (tid < 128) {
        int abs0 = base + lc[tid] - v;
        cur[tid] = abs0;
        const int n = (b << 7) + tid;
        if (n < N_NODES) { ofs[n] = abs0; oen[n] = abs0 + v; }
    }
    __syncthreads();
    for (int i = tid; i < m; i += 256) {
        int p = sP[i];
        int r = atomicAdd(&cur[p >> 17], 1);
        pairs[r] = p & 0x1FFFF;
    }
}

// ---------------------------------------------------------------------------
// K4: gather-aggregate on y: h1_i = (2+eps)*y_i + sum_nbr y_j + b1.
// Persistent grid-stride (node per wave); BN stats accumulated in registers,
// block-reduced in LDS, flushed via atomics into NREP replicas.
// ---------------------------------------------------------------------------
__launch_bounds__(256)
__global__ void gather_aggr(const __half* __restrict__ yh,
                            const int* __restrict__ adj, const int* __restrict__ ofs,
                            const int* __restrict__ oen, const float* __restrict__ eps_p,
                            const float* __restrict__ b1,
                            float* __restrict__ h1, float* __restrict__ stats) {
    const int wv   = threadIdx.x >> 6;
    const int lane = threadIdx.x & 63;
    const int wave = blockIdx.x * 4 + wv;
    const __half2* xp = (const __half2*)yh;
    const float sc = 2.0f + eps_p[0];
    const float2 b1c = ((const float2*)b1)[lane];
    float sx = 0.f, sy = 0.f, qx = 0.f, qy = 0.f;

    for (int node = wave; node < N_NODES; node += GWAVES) {
        int b = ofs[node];
        int e = oen[node];
        float ax = 0.f, ay = 0.f;
        int i = b;
        for (; i + 8 <= e; i += 8) {
            int n0 = adj[i],     n1 = adj[i + 1], n2 = adj[i + 2], n3 = adj[i + 3];
            int n4 = adj[i + 4], n5 = adj[i + 5], n6 = adj[i + 6], n7 = adj[i + 7];
            __half2 v0 = xp[(unsigned)n0 * 64u + lane];
            __half2 v1 = xp[(unsigned)n1 * 64u + lane];
            __half2 v2 = xp[(unsigned)n2 * 64u + lane];
            __half2 v3 = xp[(unsigned)n3 * 64u + lane];
            __half2 v4 = xp[(unsigned)n4 * 64u + lane];
            __half2 v5 = xp[(unsigned)n5 * 64u + lane];
            __half2 v6 = xp[(unsigned)n6 * 64u + lane];
            __half2 v7 = xp[(unsigned)n7 * 64u + lane];
            float2 f0 = __half22float2(v0);
            float2 f1 = __half22float2(v1);
            float2 f2 = __half22float2(v2);
            float2 f3 = __half22float2(v3);
            float2 f4 = __half22float2(v4);
            float2 f5 = __half22float2(v5);
            float2 f6 = __half22float2(v6);
            float2 f7 = __half22float2(v7);
            ax += ((f0.x + f1.x) + (f2.x + f3.x)) + ((f4.x + f5.x) + (f6.x + f7.x));
            ay += ((f0.y + f1.y) + (f2.y + f3.y)) + ((f4.y + f5.y) + (f6.y + f7.y));
        }
        for (; i + 4 <= e; i += 4) {
            int n0 = adj[i], n1 = adj[i + 1], n2 = adj[i + 2], n3 = adj[i + 3];
            __half2 v0 = xp[(unsigned)n0 * 64u + lane];
            __half2 v1 = xp[(unsigned)n1 * 64u + lane];
            __half2 v2 = xp[(unsigned)n2 * 64u + lane];
            __half2 v3 = xp[(unsigned)n3 * 64u + lane];
            float2 f0 = __half22float2(v0);
            float2 f1 = __half22float2(v1);
            float2 f2 = __half22float2(v2);
            float2 f3 = __half22float2(v3);
            ax += (f0.x + f1.x) + (f2.x + f3.x);
            ay += (f0.y + f1.y) + (f2.y + f3.y);
        }
        for (; i < e; ++i) {
            __half2 v = xp[(unsigned)adj[i] * 64u + lane];
            float2 f = __half22float2(v);
            ax += f.x;
            ay += f.y;
        }
        float2 ys = __half22float2(xp[(unsigned)node * 64u + lane]);
        float ox = fmaf(sc, ys.x, ax) + b1c.x;
        float oy = fmaf(sc, ys.y, ay) + b1c.y;
        ((float2*)h1)[(long long)node * 64 + lane] = make_float2(ox, oy);
        sx += ox; sy += oy;
        qx += ox * ox; qy += oy * oy;
    }

    __shared__ float4 red[4][64];
    red[wv][lane] = make_float4(sx, sy, qx, qy);
    __syncthreads();
    if (wv == 0) {
        float4 a = red[0][lane], b4 = red[1][lane], c = red[2][lane], d4 = red[3][lane];
        float fx = (a.x + b4.x) + (c.x + d4.x);
        float fy = (a.y + b4.y) + (c.y + d4.y);
        float gx = (a.z + b4.z) + (c.z + d4.z);
        float gy = (a.w + b4.w) + (c.w + d4.w);
        float* st = stats + (blockIdx.x & (NREP - 1)) * 256;
        atomicAdd(&st[2 * lane],       fx);
        atomicAdd(&st[2 * lane + 1],   fy);
        atomicAdd(&st[128 + 2 * lane],     gx);
        atomicAdd(&st[128 + 2 * lane + 1], gy);
    }
}

// ---------------------------------------------------------------------------
// K6: out = relu(bn(h1)) @ W2^T + b2  (persistent-B MFMA, grid-strided,
// prefetch), in-place on d_out. Reduces the NREP stat replicas in prologue.
// ---------------------------------------------------------------------------
__launch_bounds__(256)
__global__ void gemm2_mfma(float* __restrict__ h1out,
                           const unsigned short* __restrict__ w2h,
                           const unsigned short* __restrict__ w2l,
                           const float* __restrict__ b2, const float* __restrict__ stats,
                           const float* __restrict__ gamma, const float* __restrict__ beta) {
    __shared__ unsigned short sH[TM][136];
    __shared__ unsigned short sL[TM][136];
    __shared__ float sScale[128];
    __shared__ float sShift[128];
    const int tid = threadIdx.x;
    const int wv  = tid >> 6;
    const int ln  = tid & 63;
    const int lc  = ln & 15;
    const int qd  = ln >> 4;
    const int sr  = tid >> 5;      // staging row base (0..7)
    const int sc4 = tid & 31;      // staging float4 chunk

    if (tid < 128) {
        float s = 0.f, q = 0.f;
#pragma unroll
        for (int r = 0; r < NREP; ++r) {
            s += stats[r * 256 + tid];
            q += stats[r * 256 + 128 + tid];
        }
        float mean = s * (1.0f / N_NODES);
        float var  = fmaxf(q * (1.0f / N_NODES) - mean * mean, 0.0f);
        float sc   = gamma[tid] * rsqrtf(var + BN_EPS);
        sScale[tid] = sc;
        sShift[tid] = beta[tid] - mean * sc;
    }

    short8 Bh[4][2], Bl[4][2];
#pragma unroll
    for (int kk = 0; kk < 4; ++kk)
#pragma unroll
        for (int tl = 0; tl < 2; ++tl) {
            int woff = (wv * 32 + tl * 16 + lc) * D + kk * 32 + qd * 8;
            Bh[kk][tl] = *(const short8*)(w2h + woff);
            Bl[kk][tl] = *(const short8*)(w2l + woff);
        }
    float bb[2];
    bb[0] = b2[wv * 32 + lc];
    bb[1] = b2[wv * 32 + 16 + lc];

    __syncthreads();   // sScale/sShift ready

    float4 pf[8];
    int tile = blockIdx.x;
#pragma unroll
    for (int i = 0; i < 8; ++i) {
        int gr = tile * TM + sr + i * 8;
        pf[i] = make_float4(0.f, 0.f, 0.f, 0.f);
        if (gr < N_NODES)
            pf[i] = *(const float4*)(h1out + (long long)gr * D + sc4 * 4);
    }

    while (tile < NT) {
        float4 scv = *(const float4*)&sScale[sc4 * 4];
        float4 shv = *(const float4*)&sShift[sc4 * 4];
#pragma unroll
        for (int i = 0; i < 8; ++i) {
            int gr = tile * TM + sr + i * 8;
            float4 v = pf[i];
            if (gr < N_NODES) {
                v.x = fmaxf(0.f, fmaf(v.x, scv.x, shv.x));
                v.y = fmaxf(0.f, fmaf(v.y, scv.y, shv.y));
                v.z = fmaxf(0.f, fmaf(v.z, scv.z, shv.z));
                v.w = fmaxf(0.f, fmaf(v.w, scv.w, shv.w));
            } else {
                v = make_float4(0.f, 0.f, 0.f, 0.f);
            }
            unsigned short h0 = bf_hi(v.x), h1b = bf_hi(v.y), h2 = bf_hi(v.z), h3 = bf_hi(v.w);
            unsigned short l0 = bf_hi(v.x - bf_val(h0)), l1 = bf_hi(v.y - bf_val(h1b));
            unsigned short l2 = bf_hi(v.z - bf_val(h2)), l3 = bf_hi(v.w - bf_val(h3));
            int r = sr + i * 8;
            *(uint2*)&sH[r][sc4 * 4] = make_uint2((unsigned)h0 | ((unsigned)h1b << 16),
                                                  (unsigned)h2 | ((unsigned)h3 << 16));
            *(uint2*)&sL[r][sc4 * 4] = make_uint2((unsigned)l0 | ((unsigned)l1 << 16),
                                                  (unsigned)l2 | ((unsigned)l3 << 16));
        }
        __syncthreads();
        int nxt = tile + GGRID;
        if (nxt < NT) {
#pragma unroll
            for (int i = 0; i < 8; ++i) {
                int gr = nxt * TM + sr + i * 8;
                pf[i] = make_float4(0.f, 0.f, 0.f, 0.f);
                if (gr < N_NODES)
                    pf[i] = *(const float4*)(h1out + (long long)gr * D + sc4 * 4);
            }
        }

        f32x4 acc[4][2];
#pragma unroll
        for (int m = 0; m < 4; ++m)
#pragma unroll
            for (int tl = 0; tl < 2; ++tl) acc[m][tl] = (f32x4){0.f, 0.f, 0.f, 0.f};

#pragma unroll
        for (int kk = 0; kk < 4; ++kk) {
#pragma unroll
            for (int m = 0; m < 4; ++m) {
                short8 ah = *(const short8*)&sH[m * 16 + lc][kk * 32 + qd * 8];
                short8 al = *(const short8*)&sL[m * 16 + lc][kk * 32 + qd * 8];
#pragma unroll
                for (int tl = 0; tl < 2; ++tl) {
                    acc[m][tl] = __builtin_amdgcn_mfma_f32_16x16x32_bf16(ah, Bh[kk][tl], acc[m][tl], 0, 0, 0);
                    acc[m][tl] = __builtin_amdgcn_mfma_f32_16x16x32_bf16(al, Bh[kk][tl], acc[m][tl], 0, 0, 0);
                    acc[m][tl] = __builtin_amdgcn_mfma_f32_16x16x32_bf16(ah, Bl[kk][tl], acc[m][tl], 0, 0, 0);
                }
            }
        }

        const int row0 = tile * TM;
#pragma unroll
        for (int m = 0; m < 4; ++m)
#pragma unroll
            for (int tl = 0; tl < 2; ++tl) {
                int col = wv * 32 + tl * 16 + lc;
#pragma unroll
                for (int r = 0; r < 4; ++r) {
                    int grow = row0 + m * 16 + qd * 4 + r;
                    if (grow < N_NODES)
                        h1out[(long long)grow * D + col] = acc[m][tl][r] + bb[tl];
                }
            }
        __syncthreads();
        tile = nxt;
    }
}

// ---------------------------------------------------------------------------
extern "C" void kernel_launch(void* const* d_in, const int* in_sizes, int n_in,
                              void* d_out, int out_size, void* d_ws, size_t ws_size,
                              hipStream_t stream) {
    const float* x     = (const float*)d_in[0];
    const int*   ei    = (const int*)d_in[1];
    const float* eps_p = (const float*)d_in[2];
    const float* W1    = (const float*)d_in[3];
    const float* b1    = (const float*)d_in[4];
    const float* gamma = (const float*)d_in[5];
    const float* beta  = (const float*)d_in[6];
    const float* W2    = (const float*)d_in[7];
    const float* b2    = (const float*)d_in[8];

    // workspace layout (~42 MB)
    __half* yh   = (__half*)d_ws;                             // N*128 halfs: y mirror (25.6MB)
    float*  stats = (float*)(yh + (long long)N_NODES * D);    // NREP*256 floats
    int*    gcur  = (int*)(stats + NREP * 256);               // 1024 ints (zeroed w/ stats)
    int*    ofs   = gcur + 1024;                              // N ints
    int*    oen   = ofs + N_NODES;                            // N ints
    unsigned short* w1h = (unsigned short*)(oen + N_NODES);
    unsigned short* w1l = w1h + 16384;
    unsigned short* w2h = w1l + 16384;
    unsigned short* w2l = w2h + 16384;
    int*    pairs = (int*)(w2l + 16384);                      // NB*SLOT ints (15.0MB)
    int*    adj   = pairs;                                    // adj aliases pairs (in-place)

    float* out = (float*)d_out;                               // h1 scratch + final out

    {   // K0: zero stats/gcur + split W1/W2
        zero_split<<<128, 256, 0, stream>>>((int*)stats, W1, W2, w1h, w1l, w2h, w2l);
    }
    {   // F1: fused gemm0 (blocks 0..781) + edge partition (blocks 782..1563)
        fused_pg<<<GGRID + 782, 256, 0, stream>>>(x, w1h, w1l, yh, ei, gcur, pairs);
    }
    {   // K3b: per-bucket LDS-staged count+scan+place -> ofs/oen, adj in-place
        bucket_fill<<<NB, 256, 0, stream>>>(pairs, gcur, ofs, oen);
    }
    {   // K4: gather-aggregate on y -> h1 (d_out) + BN stats
        gather_aggr<<<GBLKS, 256, 0, stream>>>(yh, adj, ofs, oen, eps_p, b1, out, stats);
    }
    {   // K6: BN finalize + ReLU + persistent-B MFMA GEMM2, in-place on d_out
        gemm2_mfma<<<GGRID, 256, 0, stream>>>(out, w2h, w2l, b2, stats, gamma, beta);
    }
}